// Round 4
// baseline (553.137 us; speedup 1.0000x reference)
//
#include <hip/hip_runtime.h>

// GNNModel fused via fp16 MFMA 16x16x32. Adjacency bit-exact fp32.
// R4: barrier-lean structure. Ahat symmetric => mix computed as
// h_next^T = tT @ Amat (A-frags = wave-private tT rows, B-frags = AmatT
// preloaded in VGPRs), so epilogues are b64 writes and the transpose
// staging needs NO barrier. Ping-pong h_a removes the WAR barrier:
// 5 barriers total (proj, l0, l1, pool, head1) vs 8 in R3.

typedef _Float16 half8v  __attribute__((ext_vector_type(8)));
typedef _Float16 half4v  __attribute__((ext_vector_type(4)));
typedef float    float4v __attribute__((ext_vector_type(4)));

constexpr int PP = 12, DIN = 32, H = 128, HO = 64, DOUT = 3, NL = 3;
constexpr int NB = 4, ROWS = NB * PP;   // 48 rows per block
constexpr int HP  = 136;                // h_a stride (halves): 272B, 16B-mult, balanced banks
constexpr int TP  = 72;                 // tT stride: 144B, 16B-mult; K padded 48->64
constexpr int AP2 = 72;                 // AmatT stride

// ws layout in halves: WinT[128][32] @0 ; WgT[3][128][128] @4096 ; W1T[64][128] @53248
constexpr int WS_WG = 4096, WS_W1 = 53248, WS_TOT = 61440;

__global__ __launch_bounds__(256)
void prep_weights(const float* __restrict__ W_in, const float* __restrict__ W_gcn,
                  const float* __restrict__ W_out1, _Float16* __restrict__ ws)
{
    int e = blockIdx.x * 256 + threadIdx.x;
    if (e < WS_WG) {                        // WinT[n][k] = W_in[k][n]
        int n = e >> 5, k = e & 31;
        ws[e] = (_Float16)W_in[k * H + n];
    } else if (e < WS_W1) {                 // WgT[l][n][k] = W_gcn[l][k][n]
        int e2 = e - WS_WG;
        int l = e2 >> 14, r = e2 & 16383, n = r >> 7, k = r & 127;
        ws[e] = (_Float16)W_gcn[l * (H * H) + k * H + n];
    } else if (e < WS_TOT) {                // W1T[o][k] = W_out1[k][o]
        int e3 = e - WS_W1;
        int o = e3 >> 7, k = e3 & 127;
        ws[e] = (_Float16)W_out1[k * HO + o];
    }
}

__global__ __launch_bounds__(256, 3)
void gnn_mfma(const float* __restrict__ x,
              const float* __restrict__ b_in,
              const float* __restrict__ b_gcn,
              const float* __restrict__ b_out1,
              const float* __restrict__ W_out2,
              const float* __restrict__ b_out2,
              const _Float16* __restrict__ ws,
              float* __restrict__ out)
{
    __shared__ _Float16 h_a[2][ROWS][HP];           // 25.5 KB ping-pong
    __shared__ _Float16 tT[H][TP];                  // 18 KB, wave-private rows 32w..32w+31
    __shared__ __align__(16) char r3[ROWS * AP2 * 2]; // 6.75 KB: AmatT, later g_s/o1_s
    _Float16 (*AmatT)[AP2] = (_Float16 (*)[AP2])r3;
    float* g_s  = (float*)r3;                       // [NB][H], 2048 B (AmatT dead by then)
    float* o1_s = (float*)(r3 + NB * H * 4);        // [NB][HO], 1024 B

    const int tid  = threadIdx.x;
    const int lane = tid & 63, wave = tid >> 6;
    const int q = lane >> 4, qm = lane & 15;
    const int b0 = blockIdx.x * NB;
    const float* xblk = x + (size_t)b0 * (PP * DIN);

    // ---- zero tT K-pad cols [48..64) once (read as mix A-frag kt=1 tail) ----
    #pragma unroll
    for (int i = 0; i < 4; ++i) {
        int idx = tid + 256 * i;                    // 0..1023 = 128 rows x 8 dwords
        int r = idx >> 3, c = (idx & 7) * 2;
        *(unsigned*)&tT[r][48 + c] = 0u;
    }

    // ---- adjacency: wave w builds batch w (lanes 0..11), bit-exact fp32 mask ----
    if (lane < PP) {
        float lon[PP];
        #pragma unroll
        for (int j = 0; j < PP; ++j) lon[j] = xblk[(wave * PP + j) * DIN];
        float dinv[PP];
        #pragma unroll
        for (int j = 0; j < PP; ++j) {
            float deg = 1.0f;                        // GCNConv's appended self-loop
            #pragma unroll
            for (int k = 0; k < PP; ++k) {
                float d = fabsf(lon[j] - lon[k]);
                d = fminf(d, 360.0f - d);
                deg += (d < 10.0f) ? 1.0f : 0.0f;
            }
            dinv[j] = rsqrtf(fmaxf(deg, 1e-12f));
        }
        const int n = wave * PP + lane;
        #pragma unroll
        for (int c = 0; c < 64; c += 2) *(unsigned*)&AmatT[n][c] = 0u;
        const float di = dinv[lane];
        #pragma unroll
        for (int j = 0; j < PP; ++j) {
            float d = fabsf(lon[lane] - lon[j]);
            d = fminf(d, 360.0f - d);
            float a = (d < 10.0f) ? 1.0f : 0.0f;
            if (j == lane) a += 1.0f;                // A = mask + eye: diag = 2
            AmatT[n][wave * PP + j] = (_Float16)(a * di * dinv[j]);
        }
    }

    // ---- proj: h0^T = WinT @ x^T -> h_a[0][planet][col], b64 epilogue ----
    {
        half8v bx[3];
        #pragma unroll
        for (int nt = 0; nt < 3; ++nt) {
            const float* xp = xblk + (16 * nt + qm) * DIN + 8 * q;
            float4 v0 = *(const float4*)xp, v1 = *(const float4*)(xp + 4);
            half8v h;
            h[0]=(_Float16)v0.x; h[1]=(_Float16)v0.y; h[2]=(_Float16)v0.z; h[3]=(_Float16)v0.w;
            h[4]=(_Float16)v1.x; h[5]=(_Float16)v1.y; h[6]=(_Float16)v1.z; h[7]=(_Float16)v1.w;
            bx[nt] = h;
        }
        #pragma unroll
        for (int mt2 = 0; mt2 < 2; ++mt2) {
            const int m = 32 * wave + 16 * mt2;
            half8v aw = *(const half8v*)&ws[(m + qm) * DIN + 8 * q];
            float4 bi = *(const float4*)&b_in[m + 4 * q];
            #pragma unroll
            for (int nt = 0; nt < 3; ++nt) {
                float4v c = {0.f, 0.f, 0.f, 0.f};
                c = __builtin_amdgcn_mfma_f32_16x16x32_f16(aw, bx[nt], c, 0, 0, 0);
                half4v hv;
                hv[0] = (_Float16)(c[0] + bi.x); hv[1] = (_Float16)(c[1] + bi.y);
                hv[2] = (_Float16)(c[2] + bi.z); hv[3] = (_Float16)(c[3] + bi.w);
                *(half4v*)&h_a[0][16 * nt + qm][m + 4 * q] = hv;
            }
        }
    }
    __syncthreads();   // covers: proj h_a + AmatT build

    // ---- Amat B-frags, preloaded once (AmatT LDS dead afterwards) ----
    half8v amf[2][3];
    #pragma unroll
    for (int kt = 0; kt < 2; ++kt)
        #pragma unroll
        for (int nt = 0; nt < 3; ++nt)
            amf[kt][nt] = *(const half8v*)&AmatT[16 * nt + qm][32 * kt + 8 * q];

    const _Float16* WgT = ws + WS_WG;
    half8v bw[2][4];                                // layer-l W B-frags (prefetched)
    #pragma unroll
    for (int nt2 = 0; nt2 < 2; ++nt2)
        #pragma unroll
        for (int kt = 0; kt < 4; ++kt)
            bw[nt2][kt] = *(const half8v*)&WgT[(32 * wave + 16 * nt2 + qm) * H + 32 * kt + 8 * q];

    // ---- GCN layers: 1 barrier each (none after last) ----
    #pragma unroll
    for (int l = 0; l < NL; ++l) {
        const int src = l & 1, dst = src ^ 1;

        // t = h @ Wl : C-layout acc
        float4v c[3][2];
        #pragma unroll
        for (int mt = 0; mt < 3; ++mt) {
            c[mt][0] = (float4v){0.f, 0.f, 0.f, 0.f};
            c[mt][1] = (float4v){0.f, 0.f, 0.f, 0.f};
        }
        #pragma unroll
        for (int kt = 0; kt < 4; ++kt)
            #pragma unroll
            for (int mt = 0; mt < 3; ++mt) {
                half8v a = *(const half8v*)&h_a[src][16 * mt + qm][32 * kt + 8 * q];
                c[mt][0] = __builtin_amdgcn_mfma_f32_16x16x32_f16(a, bw[0][kt], c[mt][0], 0, 0, 0);
                c[mt][1] = __builtin_amdgcn_mfma_f32_16x16x32_f16(a, bw[1][kt], c[mt][1], 0, 0, 0);
            }

        // t -> tT (wave-private cols; no barrier, lgkmcnt only)
        #pragma unroll
        for (int mt = 0; mt < 3; ++mt)
            #pragma unroll
            for (int nt2 = 0; nt2 < 2; ++nt2) {
                half4v hv;
                hv[0] = (_Float16)c[mt][nt2][0]; hv[1] = (_Float16)c[mt][nt2][1];
                hv[2] = (_Float16)c[mt][nt2][2]; hv[3] = (_Float16)c[mt][nt2][3];
                *(half4v*)&tT[32 * wave + 16 * nt2 + qm][16 * mt + 4 * q] = hv;
            }

        // prefetch next layer's W frags (hidden behind mix)
        if (l + 1 < NL) {
            const _Float16* Wn = WgT + (l + 1) * (H * H);
            #pragma unroll
            for (int nt2 = 0; nt2 < 2; ++nt2)
                #pragma unroll
                for (int kt = 0; kt < 4; ++kt)
                    bw[nt2][kt] = *(const half8v*)&Wn[(32 * wave + 16 * nt2 + qm) * H + 32 * kt + 8 * q];
        }

        // mix: h_next^T = tT @ Amat (Ahat symmetric) -> b64 epilogue
        half8v ak[2][2];
        #pragma unroll
        for (int mt2 = 0; mt2 < 2; ++mt2)
            #pragma unroll
            for (int kt = 0; kt < 2; ++kt)
                ak[mt2][kt] = *(const half8v*)&tT[32 * wave + 16 * mt2 + qm][32 * kt + 8 * q];

        #pragma unroll
        for (int mt2 = 0; mt2 < 2; ++mt2) {
            float4 bg = *(const float4*)&b_gcn[l * H + 32 * wave + 16 * mt2 + 4 * q];
            #pragma unroll
            for (int nt = 0; nt < 3; ++nt) {
                float4v d = {0.f, 0.f, 0.f, 0.f};
                d = __builtin_amdgcn_mfma_f32_16x16x32_f16(ak[mt2][0], amf[0][nt], d, 0, 0, 0);
                d = __builtin_amdgcn_mfma_f32_16x16x32_f16(ak[mt2][1], amf[1][nt], d, 0, 0, 0);
                half4v hv;
                hv[0] = (_Float16)fmaxf(d[0] + bg.x, 0.f);
                hv[1] = (_Float16)fmaxf(d[1] + bg.y, 0.f);
                hv[2] = (_Float16)fmaxf(d[2] + bg.z, 0.f);
                hv[3] = (_Float16)fmaxf(d[3] + bg.w, 0.f);
                *(half4v*)&h_a[dst][16 * nt + qm][32 * wave + 16 * mt2 + 4 * q] = hv;
            }
        }
        if (l < NL - 1) __syncthreads();            // RAW only (WAR solved by ping-pong)
    }

    // ---- mean pool (wave-own cols of h_a[1]; no barrier needed before) ----
    {
        const int colw = 32 * wave + (lane & 31);
        const int bb = lane >> 5;
        #pragma unroll
        for (int s = 0; s < 2; ++s) {
            const int b = 2 * bb + s;
            float sum = 0.f;
            #pragma unroll
            for (int p = 0; p < PP; ++p) sum += (float)h_a[1][b * PP + p][colw];
            g_s[b * H + colw] = sum * (1.0f / 12.0f);
        }
    }
    __syncthreads();

    // ---- head1: o1 = relu(g @ W_out1 + b_out1) ----
    {
        const int b4 = tid >> 6, o = tid & 63;
        float acc = b_out1[o];
        const _Float16* wr = ws + WS_W1 + o * H;
        #pragma unroll
        for (int kk = 0; kk < H / 8; ++kk) {
            half8v wv = *(const half8v*)&wr[8 * kk];
            #pragma unroll
            for (int j = 0; j < 8; ++j) acc += g_s[b4 * H + 8 * kk + j] * (float)wv[j];
        }
        o1_s[b4 * HO + o] = fmaxf(acc, 0.f);
    }
    __syncthreads();

    // ---- head2 ----
    if (tid < NB * DOUT) {
        int b = tid / DOUT, o = tid - DOUT * b;
        float acc = b_out2[o];
        #pragma unroll 8
        for (int k = 0; k < HO; ++k)
            acc += o1_s[b * HO + k] * W_out2[k * DOUT + o];
        out[(size_t)(b0 + b) * DOUT + o] = acc;
    }
}

extern "C" void kernel_launch(void* const* d_in, const int* in_sizes, int n_in,
                              void* d_out, int out_size, void* d_ws, size_t ws_size,
                              hipStream_t stream) {
    const float* x      = (const float*)d_in[0];
    const float* W_in   = (const float*)d_in[1];
    const float* b_in   = (const float*)d_in[2];
    const float* W_gcn  = (const float*)d_in[3];
    const float* b_gcn  = (const float*)d_in[4];
    const float* W_out1 = (const float*)d_in[5];
    const float* b_out1 = (const float*)d_in[6];
    const float* W_out2 = (const float*)d_in[7];
    const float* b_out2 = (const float*)d_in[8];
    float* outp         = (float*)d_out;
    _Float16* wsh       = (_Float16*)d_ws;

    const int B = in_sizes[0] / (PP * DIN);         // 65536

    hipLaunchKernelGGL(prep_weights, dim3((WS_TOT + 255) / 256), dim3(256), 0, stream,
                       W_in, W_gcn, W_out1, wsh);
    hipLaunchKernelGGL(gnn_mfma, dim3(B / NB), dim3(256), 0, stream,
                       x, b_in, b_gcn, b_out1, W_out2, b_out2, wsh, outp);
}